// Round 1
// baseline (4118.114 us; speedup 1.0000x reference)
//
#include <hip/hip_runtime.h>
#include <stdint.h>

#define ALPHA_C 10.0f
#define DELTA_C 0.0005f
#define KBUCK (1u << 22)          // 4,194,304 buckets, avg 4 elems/bucket
#define SCAN_BLOCKS 1024
#define SCAN_TPB 256
#define SCAN_PER_THREAD 16        // 1024*256*16 == 2^22 == KBUCK

// Monotone non-decreasing bucket function. Must be IDENTICAL in hist/scatter/query:
// monotonicity is the only property needed for exact lo/hi bracketing.
__device__ __forceinline__ int bucket_of(float x) {
    int b = (int)(x * (float)KBUCK);      // x may be slightly <0 or >1 for queries
    b = b < 0 ? 0 : b;
    b = b > (int)KBUCK - 1 ? (int)KBUCK - 1 : b;
    return b;
}

__device__ __forceinline__ float clamp01(float x) {
    return fminf(fmaxf(x, 0.0f), 1.0f);
}

__global__ void hist_kernel(const float* __restrict__ ind, unsigned* __restrict__ off, int n) {
    int i = blockIdx.x * blockDim.x + threadIdx.x;
    if (i < n) {
        float x = clamp01(ind[i]);
        atomicAdd(&off[bucket_of(x)], 1u);
    }
}

// Block-local exclusive scan of 4096 counters; write local scan in place, block total to bsums.
__global__ void scan1(unsigned* __restrict__ off, unsigned* __restrict__ bsums) {
    __shared__ unsigned lds[SCAN_TPB];
    int base = blockIdx.x * (SCAN_TPB * SCAN_PER_THREAD) + threadIdx.x * SCAN_PER_THREAD;
    unsigned v[SCAN_PER_THREAD];
    unsigned tot = 0;
#pragma unroll
    for (int k = 0; k < SCAN_PER_THREAD; ++k) { v[k] = off[base + k]; tot += v[k]; }
    lds[threadIdx.x] = tot;
    __syncthreads();
    unsigned x = tot;
    for (int s = 1; s < SCAN_TPB; s <<= 1) {
        unsigned y = (threadIdx.x >= (unsigned)s) ? lds[threadIdx.x - s] : 0u;
        __syncthreads();
        x += y;
        lds[threadIdx.x] = x;
        __syncthreads();
    }
    if (threadIdx.x == SCAN_TPB - 1) bsums[blockIdx.x] = x;   // inclusive of whole block
    unsigned run = x - tot;                                    // exclusive prefix for this thread
#pragma unroll
    for (int k = 0; k < SCAN_PER_THREAD; ++k) { unsigned c = v[k]; off[base + k] = run; run += c; }
}

// Exclusive scan of the 1024 block sums (single block).
__global__ void scan2(unsigned* __restrict__ bsums) {
    __shared__ unsigned lds[SCAN_BLOCKS];
    int tid = threadIdx.x;
    unsigned v = bsums[tid];
    lds[tid] = v;
    __syncthreads();
    unsigned x = v;
    for (int s = 1; s < SCAN_BLOCKS; s <<= 1) {
        unsigned y = (tid >= s) ? lds[tid - s] : 0u;
        __syncthreads();
        x += y;
        lds[tid] = x;
        __syncthreads();
    }
    bsums[tid] = x - v;   // exclusive
}

__global__ void scan3(unsigned* __restrict__ off, const unsigned* __restrict__ bsums) {
    int base = blockIdx.x * (SCAN_TPB * SCAN_PER_THREAD);
    unsigned add = bsums[blockIdx.x];
#pragma unroll
    for (int k = 0; k < SCAN_PER_THREAD; ++k)
        off[base + k * SCAN_TPB + threadIdx.x] += add;
}

// Scatter (x, y) pairs into bucket regions. After this, off[b] == END of bucket b.
__global__ void scatter_kernel(const float* __restrict__ ind, const float* __restrict__ arr,
                               unsigned* __restrict__ off, float2* __restrict__ buck, int n) {
    int i = blockIdx.x * blockDim.x + threadIdx.x;
    if (i < n) {
        float x = clamp01(ind[i]);
        unsigned p = atomicAdd(&off[bucket_of(x)], 1u);
        buck[p] = make_float2(x, arr[i]);
    }
}

// f(q): find max{x<=q} and min{x>q} via bucket scan; walk to first nonempty
// neighbor bucket if a side is missing. Exact bracketing by monotonicity of bucket_of.
__device__ float feval(float q, const unsigned* __restrict__ off, const float2* __restrict__ buck) {
    int b = bucket_of(q);
    unsigned s = (b == 0) ? 0u : off[b - 1];
    unsigned e = off[b];
    float loX = -1e30f, loY = 0.0f, hiX = 1e30f, hiY = 0.0f;
    for (unsigned u = s; u < e; ++u) {
        float2 p = buck[u];
        if (p.x <= q) { if (p.x >= loX) { loX = p.x; loY = p.y; } }
        else          { if (p.x <  hiX) { hiX = p.x; hiY = p.y; } }
    }
    if (loX == -1e30f) {           // walk left: first nonempty bucket, all elems < q
        int bl = b;
        while (bl > 0) {
            --bl;
            unsigned s2 = (bl == 0) ? 0u : off[bl - 1];
            unsigned e2 = off[bl];
            if (e2 > s2) {
                for (unsigned u = s2; u < e2; ++u) {
                    float2 p = buck[u];
                    if (p.x >= loX) { loX = p.x; loY = p.y; }
                }
                break;
            }
        }
    }
    if (hiX == 1e30f) {            // walk right: first nonempty bucket, all elems > q
        int br = b;
        while (br < (int)KBUCK - 1) {
            ++br;
            unsigned s2 = off[br - 1];
            unsigned e2 = off[br];
            if (e2 > s2) {
                for (unsigned u = s2; u < e2; ++u) {
                    float2 p = buck[u];
                    if (p.x < hiX) { hiX = p.x; hiY = p.y; }
                }
                break;
            }
        }
    }
    if (loX == -1e30f) return hiY;   // q below all knots -> y of min x
    if (hiX ==  1e30f) return loY;   // q above all knots -> y of max x
    return loY + (q - loX) * (hiY - loY) / (hiX - loX);
}

__global__ void query_kernel(const float* __restrict__ ind, const unsigned* __restrict__ off,
                             const float2* __restrict__ buck, float* __restrict__ out, int nterm) {
    int j = blockIdx.x * blockDim.x + threadIdx.x;
    float term = 0.0f;
    if (j < nterm) {
        float c0 = clamp01(ind[j]);
        float c1 = clamp01(ind[j + 1]);
        float fa = feval(c0 + DELTA_C, off, buck);
        float fb = feval(c1 - DELTA_C, off, buck);
        term = fmaxf(fa - fb, 0.0f);
    }
    // wave(64) reduce then block reduce, one atomic per block
    float w = term;
    for (int s = 32; s > 0; s >>= 1) w += __shfl_down(w, s, 64);
    __shared__ float wsum[4];   // 256 threads = 4 waves
    if ((threadIdx.x & 63) == 0) wsum[threadIdx.x >> 6] = w;
    __syncthreads();
    if (threadIdx.x == 0) {
        float t = wsum[0] + wsum[1] + wsum[2] + wsum[3];
        atomicAdd(out, ALPHA_C * t);
    }
}

extern "C" void kernel_launch(void* const* d_in, const int* in_sizes, int n_in,
                              void* d_out, int out_size, void* d_ws, size_t ws_size,
                              hipStream_t stream) {
    const float* ind = (const float*)d_in[0];
    const float* arr = (const float*)d_in[1];
    float* out = (float*)d_out;
    int n = in_sizes[0];

    // workspace layout: off[KBUCK] (16MB) | bsums[1024] (+pad to 4KB) | buck[n] float2 (128MB)
    uint8_t* w8 = (uint8_t*)d_ws;
    unsigned* off = (unsigned*)w8;
    unsigned* bsums = (unsigned*)(w8 + (size_t)KBUCK * 4);
    float2* buck = (float2*)(w8 + (size_t)KBUCK * 4 + 4096);

    hipMemsetAsync(off, 0, (size_t)KBUCK * 4, stream);
    hipMemsetAsync(out, 0, sizeof(float) * (size_t)out_size, stream);

    const int tpb = 256;
    int nblk = (n + tpb - 1) / tpb;
    hist_kernel<<<nblk, tpb, 0, stream>>>(ind, off, n);
    scan1<<<SCAN_BLOCKS, SCAN_TPB, 0, stream>>>(off, bsums);
    scan2<<<1, SCAN_BLOCKS, 0, stream>>>(bsums);
    scan3<<<SCAN_BLOCKS, SCAN_TPB, 0, stream>>>(off, bsums);
    scatter_kernel<<<nblk, tpb, 0, stream>>>(ind, arr, off, buck, n);
    int nterm = n - 1;
    query_kernel<<<(nterm + tpb - 1) / tpb, tpb, 0, stream>>>(ind, off, buck, out, nterm);
}